// Round 5
// baseline (45.762 us; speedup 1.0000x reference)
//
#include <hip/hip_runtime.h>

#define D_MODEL 512
#define D_TOK   504
#define EPS     1e-5f
#define SQRT_D  22.627416997969522f   // sqrt(512)
#define VOCAB   2048
#define TPW     8                      // tokens per wave in gather kernel

// ---------------------------------------------------------------------------
// Kernel 1: one wave per vocab id -> unique output row table in d_ws.
// ---------------------------------------------------------------------------
__global__ __launch_bounds__(256) void build_table_kernel(
    const float* __restrict__ tok_tab,   // [2048][504]
    const float* __restrict__ typ_tab,   // [5][8]
    const float* __restrict__ gamma,     // [512]
    const float* __restrict__ beta,      // [512]
    float*       __restrict__ uniq)      // [2048][512]
{
    const int vid  = (int)((blockIdx.x * blockDim.x + threadIdx.x) >> 6);
    const int lane = (int)(threadIdx.x & 63);
    if (vid >= VOCAB) return;

    const int t = (vid >= 128) + (vid >= 256) + (vid >= 512) + (vid >= 1024);

    float v[8];
    if (lane < 63) {
        const float* row = tok_tab + (size_t)vid * D_TOK + (size_t)lane * 8;
        const float4 a = *reinterpret_cast<const float4*>(row);
        const float4 b = *reinterpret_cast<const float4*>(row + 4);
        v[0] = a.x; v[1] = a.y; v[2] = a.z; v[3] = a.w;
        v[4] = b.x; v[5] = b.y; v[6] = b.z; v[7] = b.w;
    } else {
        const float4* trow = reinterpret_cast<const float4*>(typ_tab + (size_t)t * 8);
        const float4 a = trow[0];
        const float4 b = trow[1];
        v[0] = a.x; v[1] = a.y; v[2] = a.z; v[3] = a.w;
        v[4] = b.x; v[5] = b.y; v[6] = b.z; v[7] = b.w;
    }

    float s = 0.f, s2 = 0.f;
#pragma unroll
    for (int i = 0; i < 8; ++i) { s += v[i]; s2 += v[i] * v[i]; }

#pragma unroll
    for (int off = 32; off > 0; off >>= 1) {
        s  += __shfl_xor(s,  off, 64);
        s2 += __shfl_xor(s2, off, 64);
    }

    const float inv_n = 1.0f / (float)D_MODEL;
    const float mean  = s * inv_n;
    const float var   = s2 * inv_n - mean * mean;
    const float rs    = rsqrtf(var + EPS) * SQRT_D;

    const float4 g0 = *reinterpret_cast<const float4*>(gamma + lane * 8);
    const float4 g1 = *reinterpret_cast<const float4*>(gamma + lane * 8 + 4);
    const float4 b0 = *reinterpret_cast<const float4*>(beta  + lane * 8);
    const float4 b1 = *reinterpret_cast<const float4*>(beta  + lane * 8 + 4);

    float4 o0, o1;
    o0.x = (v[0] - mean) * rs * g0.x + b0.x * SQRT_D;
    o0.y = (v[1] - mean) * rs * g0.y + b0.y * SQRT_D;
    o0.z = (v[2] - mean) * rs * g0.z + b0.z * SQRT_D;
    o0.w = (v[3] - mean) * rs * g0.w + b0.w * SQRT_D;
    o1.x = (v[4] - mean) * rs * g1.x + b1.x * SQRT_D;
    o1.y = (v[5] - mean) * rs * g1.y + b1.y * SQRT_D;
    o1.z = (v[6] - mean) * rs * g1.z + b1.z * SQRT_D;
    o1.w = (v[7] - mean) * rs * g1.w + b1.w * SQRT_D;

    float* orow = uniq + (size_t)vid * D_MODEL + (size_t)lane * 8;
    *reinterpret_cast<float4*>(orow)     = o0;
    *reinterpret_cast<float4*>(orow + 4) = o1;
}

// ---------------------------------------------------------------------------
// Kernel 2: gather-copy, 8 tokens per wave, deep ILP, few waves.
// Each wave copies 16 KB; ids broadcast-loaded up front; 2 batches of
// {8 float4 loads in flight -> 8 float4 stores}.
// ---------------------------------------------------------------------------
__global__ __launch_bounds__(256) void gather_kernel(
    const int*   __restrict__ x,
    const float* __restrict__ uniq,      // [2048][512]
    float*       __restrict__ out,       // [n_tokens][512]
    int n_tokens)
{
    const int wave = (int)((blockIdx.x * blockDim.x + threadIdx.x) >> 6);
    const int lane = (int)(threadIdx.x & 63);
    const int tok0 = wave * TPW;
    if (tok0 >= n_tokens) return;

    // 8 token ids, wave-uniform loads (broadcast), forced scalar
    const int4 xa = *reinterpret_cast<const int4*>(x + tok0);
    const int4 xb = *reinterpret_cast<const int4*>(x + tok0 + 4);
    int id[TPW];
    id[0] = __builtin_amdgcn_readfirstlane(xa.x);
    id[1] = __builtin_amdgcn_readfirstlane(xa.y);
    id[2] = __builtin_amdgcn_readfirstlane(xa.z);
    id[3] = __builtin_amdgcn_readfirstlane(xa.w);
    id[4] = __builtin_amdgcn_readfirstlane(xb.x);
    id[5] = __builtin_amdgcn_readfirstlane(xb.y);
    id[6] = __builtin_amdgcn_readfirstlane(xb.z);
    id[7] = __builtin_amdgcn_readfirstlane(xb.w);

    const size_t loff = (size_t)lane * 8;
    float* dst = out + (size_t)tok0 * D_MODEL + loff;

    // batch 0: tokens 0..3 — issue 8 loads, then 8 stores
    {
        float4 a[4], b[4];
#pragma unroll
        for (int k = 0; k < 4; ++k) {
            const float* src = uniq + (size_t)id[k] * D_MODEL + loff;
            a[k] = *reinterpret_cast<const float4*>(src);
            b[k] = *reinterpret_cast<const float4*>(src + 4);
        }
#pragma unroll
        for (int k = 0; k < 4; ++k) {
            float* d = dst + (size_t)k * D_MODEL;
            *reinterpret_cast<float4*>(d)     = a[k];
            *reinterpret_cast<float4*>(d + 4) = b[k];
        }
    }
    // batch 1: tokens 4..7
    {
        float4 a[4], b[4];
#pragma unroll
        for (int k = 0; k < 4; ++k) {
            const float* src = uniq + (size_t)id[k + 4] * D_MODEL + loff;
            a[k] = *reinterpret_cast<const float4*>(src);
            b[k] = *reinterpret_cast<const float4*>(src + 4);
        }
#pragma unroll
        for (int k = 0; k < 4; ++k) {
            float* d = dst + (size_t)(k + 4) * D_MODEL;
            *reinterpret_cast<float4*>(d)     = a[k];
            *reinterpret_cast<float4*>(d + 4) = b[k];
        }
    }
}

// ---------------------------------------------------------------------------
// Fallback (ws too small): verified Round-1 fused kernel.
// ---------------------------------------------------------------------------
__global__ __launch_bounds__(256) void fused_kernel(
    const int*   __restrict__ x,
    const float* __restrict__ tok_tab,
    const float* __restrict__ typ_tab,
    const float* __restrict__ gamma,
    const float* __restrict__ beta,
    float*       __restrict__ out,
    int n_tokens)
{
    const int wave = (int)((blockIdx.x * blockDim.x + threadIdx.x) >> 6);
    const int lane = (int)(threadIdx.x & 63);
    if (wave >= n_tokens) return;

    const int xi = x[wave];
    const int t = (xi >= 128) + (xi >= 256) + (xi >= 512) + (xi >= 1024);

    float v[8];
    if (lane < 63) {
        const float* row = tok_tab + (size_t)xi * D_TOK + (size_t)lane * 8;
        const float4 a = *reinterpret_cast<const float4*>(row);
        const float4 b = *reinterpret_cast<const float4*>(row + 4);
        v[0] = a.x; v[1] = a.y; v[2] = a.z; v[3] = a.w;
        v[4] = b.x; v[5] = b.y; v[6] = b.z; v[7] = b.w;
    } else {
        const float4* trow = reinterpret_cast<const float4*>(typ_tab + (size_t)t * 8);
        const float4 a = trow[0];
        const float4 b = trow[1];
        v[0] = a.x; v[1] = a.y; v[2] = a.z; v[3] = a.w;
        v[4] = b.x; v[5] = b.y; v[6] = b.z; v[7] = b.w;
    }

    float s = 0.f, s2 = 0.f;
#pragma unroll
    for (int i = 0; i < 8; ++i) { s += v[i]; s2 += v[i] * v[i]; }
#pragma unroll
    for (int off = 32; off > 0; off >>= 1) {
        s  += __shfl_xor(s,  off, 64);
        s2 += __shfl_xor(s2, off, 64);
    }

    const float inv_n = 1.0f / (float)D_MODEL;
    const float mean  = s * inv_n;
    const float var   = s2 * inv_n - mean * mean;
    const float rs    = rsqrtf(var + EPS) * SQRT_D;

    const float4 g0 = *reinterpret_cast<const float4*>(gamma + lane * 8);
    const float4 g1 = *reinterpret_cast<const float4*>(gamma + lane * 8 + 4);
    const float4 b0 = *reinterpret_cast<const float4*>(beta  + lane * 8);
    const float4 b1 = *reinterpret_cast<const float4*>(beta  + lane * 8 + 4);

    float4 o0, o1;
    o0.x = (v[0] - mean) * rs * g0.x + b0.x * SQRT_D;
    o0.y = (v[1] - mean) * rs * g0.y + b0.y * SQRT_D;
    o0.z = (v[2] - mean) * rs * g0.z + b0.z * SQRT_D;
    o0.w = (v[3] - mean) * rs * g0.w + b0.w * SQRT_D;
    o1.x = (v[4] - mean) * rs * g1.x + b1.x * SQRT_D;
    o1.y = (v[5] - mean) * rs * g1.y + b1.y * SQRT_D;
    o1.z = (v[6] - mean) * rs * g1.z + b1.z * SQRT_D;
    o1.w = (v[7] - mean) * rs * g1.w + b1.w * SQRT_D;

    float* orow = out + (size_t)wave * D_MODEL + (size_t)lane * 8;
    *reinterpret_cast<float4*>(orow)     = o0;
    *reinterpret_cast<float4*>(orow + 4) = o1;
}

extern "C" void kernel_launch(void* const* d_in, const int* in_sizes, int n_in,
                              void* d_out, int out_size, void* d_ws, size_t ws_size,
                              hipStream_t stream) {
    const int*   x       = (const int*)d_in[0];
    const float* tok_tab = (const float*)d_in[1];
    const float* typ_tab = (const float*)d_in[2];
    const float* gamma   = (const float*)d_in[3];
    const float* beta    = (const float*)d_in[4];
    float*       out     = (float*)d_out;

    const int n_tokens = in_sizes[0];   // 65536
    const size_t need  = (size_t)VOCAB * D_MODEL * sizeof(float);  // 4 MiB

    if (ws_size >= need && (n_tokens % TPW) == 0) {
        float* uniq = (float*)d_ws;
        build_table_kernel<<<(VOCAB * 64) / 256, 256, 0, stream>>>(
            tok_tab, typ_tab, gamma, beta, uniq);
        // 65536 tokens / 8 per wave = 8192 waves = 2048 blocks of 256
        const int waves  = n_tokens / TPW;
        const int blocks = (waves * 64) / 256;
        gather_kernel<<<blocks, 256, 0, stream>>>(x, uniq, out, n_tokens);
    } else {
        fused_kernel<<<(n_tokens * 64) / 256, 256, 0, stream>>>(
            x, tok_tab, typ_tab, gamma, beta, out, n_tokens);
    }
}

// Round 6
// 37.697 us; speedup vs baseline: 1.2139x; 1.2139x over previous
//
#include <hip/hip_runtime.h>

#define D_MODEL 512
#define D_TOK   504
#define EPS     1e-5f
#define SQRT_D  22.627416997969522f   // sqrt(512)

#define NBLK  4096
#define WPB   4                       // waves per block (256 thr)
#define NWAVE (NBLK * WPB)            // 16384 persistent waves
#define ITER  4                       // tokens per wave (65536 / 16384)

// ---------------------------------------------------------------------------
// Persistent, fully-unrolled, distance-1 software-pipelined fused kernel.
// Wave w processes tokens w, w+NWAVE, w+2*NWAVE, w+3*NWAVE: at any instant
// all in-flight stores cover one contiguous ~32MB span (fill-like locality),
// and token j+1's row loads are issued before token j's reduce+store.
// ---------------------------------------------------------------------------
__global__ __launch_bounds__(256) void fused_pipe_kernel(
    const int*   __restrict__ x,
    const float* __restrict__ tok_tab,   // [2048][504]
    const float* __restrict__ typ_tab,   // [5][8]
    const float* __restrict__ gamma,     // [512]
    const float* __restrict__ beta,      // [512]
    float*       __restrict__ out)       // [NWAVE*ITER][512]
{
    const int wave = (int)(blockIdx.x * WPB + (threadIdx.x >> 6));
    const int lane = (int)(threadIdx.x & 63);
    const size_t loff = (size_t)lane * 8;

    // gamma/beta once per wave (beta pre-scaled by sqrt(d))
    const float4 g0  = *reinterpret_cast<const float4*>(gamma + loff);
    const float4 g1  = *reinterpret_cast<const float4*>(gamma + loff + 4);
    const float4 bb0 = *reinterpret_cast<const float4*>(beta + loff);
    const float4 bb1 = *reinterpret_cast<const float4*>(beta + loff + 4);
    const float4 bs0 = make_float4(bb0.x * SQRT_D, bb0.y * SQRT_D, bb0.z * SQRT_D, bb0.w * SQRT_D);
    const float4 bs1 = make_float4(bb1.x * SQRT_D, bb1.y * SQRT_D, bb1.z * SQRT_D, bb1.w * SQRT_D);

    // preload all ITER ids (independent wave-uniform loads), force scalar
    int id[ITER];
#pragma unroll
    for (int j = 0; j < ITER; ++j)
        id[j] = x[wave + j * NWAVE];
#pragma unroll
    for (int j = 0; j < ITER; ++j)
        id[j] = __builtin_amdgcn_readfirstlane(id[j]);

    // row pointer for a given vocab id (lane 63 -> 8-float type row)
    auto rowptr = [&](int xi) -> const float* {
        const int t = (xi >= 128) + (xi >= 256) + (xi >= 512) + (xi >= 1024);
        const float* tokrow = tok_tab + (size_t)xi * D_TOK + loff;
        const float* typrow = typ_tab + (size_t)t * 8;
        return (lane == 63) ? typrow : tokrow;
    };

    float4 a0, b0, a1, b1;   // double buffer (all indices compile-time)
    {
        const float* r = rowptr(id[0]);
        a0 = *reinterpret_cast<const float4*>(r);
        b0 = *reinterpret_cast<const float4*>(r + 4);
    }

#pragma unroll
    for (int j = 0; j < ITER; ++j) {
        // prefetch next token's row before touching current data
        if (j + 1 < ITER) {
            const float* r = rowptr(id[j + 1]);
            if ((j & 1) == 0) {
                a1 = *reinterpret_cast<const float4*>(r);
                b1 = *reinterpret_cast<const float4*>(r + 4);
            } else {
                a0 = *reinterpret_cast<const float4*>(r);
                b0 = *reinterpret_cast<const float4*>(r + 4);
            }
        }

        const float4 a = ((j & 1) == 0) ? a0 : a1;
        const float4 b = ((j & 1) == 0) ? b0 : b1;

        float s  = a.x + a.y + a.z + a.w + b.x + b.y + b.z + b.w;
        float s2 = a.x * a.x + a.y * a.y + a.z * a.z + a.w * a.w
                 + b.x * b.x + b.y * b.y + b.z * b.z + b.w * b.w;
#pragma unroll
        for (int off = 32; off > 0; off >>= 1) {
            s  += __shfl_xor(s,  off, 64);
            s2 += __shfl_xor(s2, off, 64);
        }

        const float inv_n = 1.0f / (float)D_MODEL;
        const float mean  = s * inv_n;
        const float var   = s2 * inv_n - mean * mean;
        const float rs    = rsqrtf(var + EPS) * SQRT_D;

        float4 o0, o1;
        o0.x = (a.x - mean) * rs * g0.x + bs0.x;
        o0.y = (a.y - mean) * rs * g0.y + bs0.y;
        o0.z = (a.z - mean) * rs * g0.z + bs0.z;
        o0.w = (a.w - mean) * rs * g0.w + bs0.w;
        o1.x = (b.x - mean) * rs * g1.x + bs1.x;
        o1.y = (b.y - mean) * rs * g1.y + bs1.y;
        o1.z = (b.z - mean) * rs * g1.z + bs1.z;
        o1.w = (b.w - mean) * rs * g1.w + bs1.w;

        float* orow = out + (size_t)(wave + j * NWAVE) * D_MODEL + loff;
        *reinterpret_cast<float4*>(orow)     = o0;
        *reinterpret_cast<float4*>(orow + 4) = o1;
    }
}

// ---------------------------------------------------------------------------
// Fallback for any other token count: verified Round-1 fused kernel (38 us).
// ---------------------------------------------------------------------------
__global__ __launch_bounds__(256) void fused_kernel(
    const int*   __restrict__ x,
    const float* __restrict__ tok_tab,
    const float* __restrict__ typ_tab,
    const float* __restrict__ gamma,
    const float* __restrict__ beta,
    float*       __restrict__ out,
    int n_tokens)
{
    const int wave = (int)((blockIdx.x * blockDim.x + threadIdx.x) >> 6);
    const int lane = (int)(threadIdx.x & 63);
    if (wave >= n_tokens) return;

    const int xi = x[wave];
    const int t = (xi >= 128) + (xi >= 256) + (xi >= 512) + (xi >= 1024);

    float v[8];
    if (lane < 63) {
        const float* row = tok_tab + (size_t)xi * D_TOK + (size_t)lane * 8;
        const float4 a = *reinterpret_cast<const float4*>(row);
        const float4 b = *reinterpret_cast<const float4*>(row + 4);
        v[0] = a.x; v[1] = a.y; v[2] = a.z; v[3] = a.w;
        v[4] = b.x; v[5] = b.y; v[6] = b.z; v[7] = b.w;
    } else {
        const float4* trow = reinterpret_cast<const float4*>(typ_tab + (size_t)t * 8);
        const float4 a = trow[0];
        const float4 b = trow[1];
        v[0] = a.x; v[1] = a.y; v[2] = a.z; v[3] = a.w;
        v[4] = b.x; v[5] = b.y; v[6] = b.z; v[7] = b.w;
    }

    float s = 0.f, s2 = 0.f;
#pragma unroll
    for (int i = 0; i < 8; ++i) { s += v[i]; s2 += v[i] * v[i]; }
#pragma unroll
    for (int off = 32; off > 0; off >>= 1) {
        s  += __shfl_xor(s,  off, 64);
        s2 += __shfl_xor(s2, off, 64);
    }

    const float inv_n = 1.0f / (float)D_MODEL;
    const float mean  = s * inv_n;
    const float var   = s2 * inv_n - mean * mean;
    const float rs    = rsqrtf(var + EPS) * SQRT_D;

    const float4 g0 = *reinterpret_cast<const float4*>(gamma + lane * 8);
    const float4 g1 = *reinterpret_cast<const float4*>(gamma + lane * 8 + 4);
    const float4 b0 = *reinterpret_cast<const float4*>(beta  + lane * 8);
    const float4 b1 = *reinterpret_cast<const float4*>(beta  + lane * 8 + 4);

    float4 o0, o1;
    o0.x = (v[0] - mean) * rs * g0.x + b0.x * SQRT_D;
    o0.y = (v[1] - mean) * rs * g0.y + b0.y * SQRT_D;
    o0.z = (v[2] - mean) * rs * g0.z + b0.z * SQRT_D;
    o0.w = (v[3] - mean) * rs * g0.w + b0.w * SQRT_D;
    o1.x = (v[4] - mean) * rs * g1.x + b1.x * SQRT_D;
    o1.y = (v[5] - mean) * rs * g1.y + b1.y * SQRT_D;
    o1.z = (v[6] - mean) * rs * g1.z + b1.z * SQRT_D;
    o1.w = (v[7] - mean) * rs * g1.w + b1.w * SQRT_D;

    float* orow = out + (size_t)wave * D_MODEL + (size_t)lane * 8;
    *reinterpret_cast<float4*>(orow)     = o0;
    *reinterpret_cast<float4*>(orow + 4) = o1;
}

extern "C" void kernel_launch(void* const* d_in, const int* in_sizes, int n_in,
                              void* d_out, int out_size, void* d_ws, size_t ws_size,
                              hipStream_t stream) {
    const int*   x       = (const int*)d_in[0];
    const float* tok_tab = (const float*)d_in[1];
    const float* typ_tab = (const float*)d_in[2];
    const float* gamma   = (const float*)d_in[3];
    const float* beta    = (const float*)d_in[4];
    float*       out     = (float*)d_out;

    const int n_tokens = in_sizes[0];   // 65536

    if (n_tokens == NWAVE * ITER) {
        fused_pipe_kernel<<<NBLK, 256, 0, stream>>>(
            x, tok_tab, typ_tab, gamma, beta, out);
    } else {
        fused_kernel<<<(n_tokens * 64 + 255) / 256, 256, 0, stream>>>(
            x, tok_tab, typ_tab, gamma, beta, out, n_tokens);
    }
}

// Round 7
// 33.691 us; speedup vs baseline: 1.3583x; 1.1189x over previous
//
#include <hip/hip_runtime.h>

#define D_MODEL 512
#define D_TOK   504
#define EPS     1e-5f
#define SQRT_D  22.627416997969522f   // sqrt(512)

typedef float f32x4 __attribute__((ext_vector_type(4)));

// R1 structure exactly; ONLY change: nontemporal (evict-first) output stores.
__global__ __launch_bounds__(256) void musical_emb_kernel(
    const int*   __restrict__ x,
    const float* __restrict__ tok_tab,   // [2048][504]
    const float* __restrict__ typ_tab,   // [5][8]
    const float* __restrict__ gamma,     // [512]
    const float* __restrict__ beta,      // [512]
    float*       __restrict__ out,       // [n_tokens][512]
    int n_tokens)
{
    const int wave = (int)((blockIdx.x * blockDim.x + threadIdx.x) >> 6);
    const int lane = (int)(threadIdx.x & 63);
    if (wave >= n_tokens) return;

    const int xi = x[wave];
    const int t = (xi >= 128) + (xi >= 256) + (xi >= 512) + (xi >= 1024);

    float v[8];
    if (lane < 63) {
        const float* row = tok_tab + (size_t)xi * D_TOK + (size_t)lane * 8;
        const float4 a = *reinterpret_cast<const float4*>(row);
        const float4 b = *reinterpret_cast<const float4*>(row + 4);
        v[0] = a.x; v[1] = a.y; v[2] = a.z; v[3] = a.w;
        v[4] = b.x; v[5] = b.y; v[6] = b.z; v[7] = b.w;
    } else {
        const float4* trow = reinterpret_cast<const float4*>(typ_tab + (size_t)t * 8);
        const float4 a = trow[0];
        const float4 b = trow[1];
        v[0] = a.x; v[1] = a.y; v[2] = a.z; v[3] = a.w;
        v[4] = b.x; v[5] = b.y; v[6] = b.z; v[7] = b.w;
    }

    float s = 0.f, s2 = 0.f;
#pragma unroll
    for (int i = 0; i < 8; ++i) { s += v[i]; s2 += v[i] * v[i]; }

#pragma unroll
    for (int off = 32; off > 0; off >>= 1) {
        s  += __shfl_xor(s,  off, 64);
        s2 += __shfl_xor(s2, off, 64);
    }

    const float inv_n = 1.0f / (float)D_MODEL;
    const float mean  = s * inv_n;
    const float var   = s2 * inv_n - mean * mean;
    const float rs    = rsqrtf(var + EPS) * SQRT_D;

    const float4 g0 = *reinterpret_cast<const float4*>(gamma + lane * 8);
    const float4 g1 = *reinterpret_cast<const float4*>(gamma + lane * 8 + 4);
    const float4 b0 = *reinterpret_cast<const float4*>(beta  + lane * 8);
    const float4 b1 = *reinterpret_cast<const float4*>(beta  + lane * 8 + 4);

    f32x4 o0, o1;
    o0.x = (v[0] - mean) * rs * g0.x + b0.x * SQRT_D;
    o0.y = (v[1] - mean) * rs * g0.y + b0.y * SQRT_D;
    o0.z = (v[2] - mean) * rs * g0.z + b0.z * SQRT_D;
    o0.w = (v[3] - mean) * rs * g0.w + b0.w * SQRT_D;
    o1.x = (v[4] - mean) * rs * g1.x + b1.x * SQRT_D;
    o1.y = (v[5] - mean) * rs * g1.y + b1.y * SQRT_D;
    o1.z = (v[6] - mean) * rs * g1.z + b1.z * SQRT_D;
    o1.w = (v[7] - mean) * rs * g1.w + b1.w * SQRT_D;

    float* orow = out + (size_t)wave * D_MODEL + (size_t)lane * 8;
    __builtin_nontemporal_store(o0, reinterpret_cast<f32x4*>(orow));
    __builtin_nontemporal_store(o1, reinterpret_cast<f32x4*>(orow + 4));
}

extern "C" void kernel_launch(void* const* d_in, const int* in_sizes, int n_in,
                              void* d_out, int out_size, void* d_ws, size_t ws_size,
                              hipStream_t stream) {
    const int*   x       = (const int*)d_in[0];
    const float* tok_tab = (const float*)d_in[1];
    const float* typ_tab = (const float*)d_in[2];
    const float* gamma   = (const float*)d_in[3];
    const float* beta    = (const float*)d_in[4];
    float*       out     = (float*)d_out;

    const int n_tokens = in_sizes[0];            // 65536
    const int threads  = 256;
    const int blocks   = (n_tokens * 64 + threads - 1) / threads;

    musical_emb_kernel<<<blocks, threads, 0, stream>>>(
        x, tok_tab, typ_tab, gamma, beta, out, n_tokens);
}

// Round 8
// 28.816 us; speedup vs baseline: 1.5881x; 1.1692x over previous
//
#include <hip/hip_runtime.h>

#define D_MODEL 512
#define D_TOK   504
#define EPS     1e-5f
#define SQRT_D  22.627416997969522f   // sqrt(512)

typedef float f32x4 __attribute__((ext_vector_type(4)));

// R7 (R1 + nt stores) with ONE change: contiguous element->lane mapping.
// Lane l owns elements [4l,4l+4) and [256+4l,256+4l+4), so every global
// load/store instruction covers a fully-contiguous 1KB span (16B/lane),
// matching the fill kernel's write pattern.
__global__ __launch_bounds__(256) void musical_emb_kernel(
    const int*   __restrict__ x,
    const float* __restrict__ tok_tab,   // [2048][504]
    const float* __restrict__ typ_tab,   // [5][8]
    const float* __restrict__ gamma,     // [512]
    const float* __restrict__ beta,      // [512]
    float*       __restrict__ out,       // [n_tokens][512]
    int n_tokens)
{
    const int wave = (int)((blockIdx.x * blockDim.x + threadIdx.x) >> 6);
    const int lane = (int)(threadIdx.x & 63);
    if (wave >= n_tokens) return;

    const int xi = x[wave];
    const int t = (xi >= 128) + (xi >= 256) + (xi >= 512) + (xi >= 1024);

    const size_t offA = (size_t)lane * 4;        // elements 0..255
    const size_t offB = 256 + (size_t)lane * 4;  // elements 256..511

    // Part A: always token row (elements 0..255 < 504)
    const float4 a = *reinterpret_cast<const float4*>(tok_tab + (size_t)xi * D_TOK + offA);

    // Part B: token row for lanes 0..61; lanes 62/63 take type row [0..3]/[4..7]
    const float* pB = tok_tab + (size_t)xi * D_TOK + offB;          // e = 256+4l
    const float* pT = typ_tab + (size_t)t * 8 + (size_t)(lane - 62) * 4;
    const float4 b = *reinterpret_cast<const float4*>((lane >= 62) ? pT : pB);

    float s  = a.x + a.y + a.z + a.w + b.x + b.y + b.z + b.w;
    float s2 = a.x * a.x + a.y * a.y + a.z * a.z + a.w * a.w
             + b.x * b.x + b.y * b.y + b.z * b.z + b.w * b.w;

#pragma unroll
    for (int off = 32; off > 0; off >>= 1) {
        s  += __shfl_xor(s,  off, 64);
        s2 += __shfl_xor(s2, off, 64);
    }

    const float inv_n = 1.0f / (float)D_MODEL;
    const float mean  = s * inv_n;
    const float var   = s2 * inv_n - mean * mean;
    const float rs    = rsqrtf(var + EPS) * SQRT_D;

    const float4 g0 = *reinterpret_cast<const float4*>(gamma + offA);
    const float4 g1 = *reinterpret_cast<const float4*>(gamma + offB);
    const float4 b0 = *reinterpret_cast<const float4*>(beta  + offA);
    const float4 b1 = *reinterpret_cast<const float4*>(beta  + offB);

    f32x4 o0, o1;
    o0.x = (a.x - mean) * rs * g0.x + b0.x * SQRT_D;
    o0.y = (a.y - mean) * rs * g0.y + b0.y * SQRT_D;
    o0.z = (a.z - mean) * rs * g0.z + b0.z * SQRT_D;
    o0.w = (a.w - mean) * rs * g0.w + b0.w * SQRT_D;
    o1.x = (b.x - mean) * rs * g1.x + b1.x * SQRT_D;
    o1.y = (b.y - mean) * rs * g1.y + b1.y * SQRT_D;
    o1.z = (b.z - mean) * rs * g1.z + b1.z * SQRT_D;
    o1.w = (b.w - mean) * rs * g1.w + b1.w * SQRT_D;

    float* orow = out + (size_t)wave * D_MODEL;
    __builtin_nontemporal_store(o0, reinterpret_cast<f32x4*>(orow + offA));
    __builtin_nontemporal_store(o1, reinterpret_cast<f32x4*>(orow + offB));
}

extern "C" void kernel_launch(void* const* d_in, const int* in_sizes, int n_in,
                              void* d_out, int out_size, void* d_ws, size_t ws_size,
                              hipStream_t stream) {
    const int*   x       = (const int*)d_in[0];
    const float* tok_tab = (const float*)d_in[1];
    const float* typ_tab = (const float*)d_in[2];
    const float* gamma   = (const float*)d_in[3];
    const float* beta    = (const float*)d_in[4];
    float*       out     = (float*)d_out;

    const int n_tokens = in_sizes[0];            // 65536
    const int threads  = 256;
    const int blocks   = (n_tokens * 64 + threads - 1) / threads;

    musical_emb_kernel<<<blocks, threads, 0, stream>>>(
        x, tok_tab, typ_tab, gamma, beta, out, n_tokens);
}